// Round 2
// baseline (961.123 us; speedup 1.0000x reference)
//
#include <hip/hip_runtime.h>

typedef __attribute__((ext_vector_type(8))) short short8;
typedef __attribute__((ext_vector_type(4))) float floatx4;

#define MFMA(a,b,c) __builtin_amdgcn_mfma_f32_16x16x32_bf16(a,b,c,0,0,0)

__device__ __forceinline__ ushort f2bf(float f){ union{float f;uint i;}x; x.f=f; return (ushort)((x.i + 0x7fffu + ((x.i>>16)&1u))>>16); }
__device__ __forceinline__ short8 lds8(const ushort* p){ return *(const short8*)p; }

// ---------------------------------------------------------------------------
// Prologue: convert GEMM weights fp32 -> bf16 into ws.
// qkv_w @0 (27648), proj_w @27648 (9216), fc1_w @36864 (36864), fc2_w @73728 (36864)
// ---------------------------------------------------------------------------
__global__ void convw_kernel(const float* __restrict__ qkvw,
                             const float* __restrict__ projw,
                             const float* __restrict__ f1w,
                             const float* __restrict__ f2w,
                             ushort* __restrict__ wb)
{
  int i = blockIdx.x*256 + threadIdx.x;
  float v;
  if      (i < 27648)  v = qkvw[i];
  else if (i < 36864)  v = projw[i-27648];
  else if (i < 73728)  v = f1w[i-36864];
  else if (i < 110592) v = f2w[i-73728];
  else return;
  wb[i] = f2bf(v);
}

// ---------------------------------------------------------------------------
// Fully fused Swin block. One workgroup (256 thr = 4 waves) per window.
// Round-1 restructure: every GEMM wave computes ALL 64 rows for a column
// subset, holding 12 A-fragments in registers -> each weight B-fragment is
// loaded once and reused across 4 row-tiles (2 for fc2). Weight loads/block
// drop 864 -> ~332. spos[] caches per-token global offsets (kills div/7 math).
// ---------------------------------------------------------------------------
__global__ __launch_bounds__(256,4) void swin_block_kernel(
    const float* __restrict__ x,
    const float* __restrict__ g1, const float* __restrict__ b1v,
    const ushort* __restrict__ qkv_wb, const float* __restrict__ qkv_b,
    const ushort* __restrict__ proj_wb, const float* __restrict__ proj_b,
    const float* __restrict__ g2, const float* __restrict__ b2v,
    const ushort* __restrict__ fc1_wb, const float* __restrict__ fc1_b,
    const ushort* __restrict__ fc2_wb, const float* __restrict__ fc2_b,
    float* __restrict__ out)
{
  __shared__ __align__(16) ushort sm[19456];        // 38912 B
  __shared__ int sid[64];
  __shared__ int spos[64];
  ushort* xn  = sm;                    // 64x104 bf16: LN1 out -> attn O -> LN2 out
  ushort* Qh  = sm + 6656;             // [64][40]  current head (stride 80B: conflict-free)
  ushort* Kh  = sm + 9216;             // [64][40]  current head
  ushort* Vh  = sm + 11776;            // [32][72]  [d][token], current head
  ushort* Pb  = sm + 14080;            // [64][72]
  float*  xrb = (float*)(sm + 6656);   // 64x96 fp32 residual (phases 3-4 only)
  ushort* hb  = sm + 6656;             // [64][200] bf16 MLP hidden half (phase 5)

  const int tid  = threadIdx.x;
  const int w    = blockIdx.x;
  const int b    = w >> 10;
  const int wh   = (w >> 5) & 31;
  const int wwn  = w & 31;
  const int lane = tid & 63;
  const int wv   = tid >> 6;
  const int quad = lane >> 4;
  const int ln   = lane & 15;

  // ---- Phase 0: LN1 + shifted-window gather (4 threads per token) ----
  {
    const int n = tid >> 2, q = tid & 3;
    if (n < 49) {
      const int i = n / 7, j = n - 7*i;
      int hh = wh*7 + i + 3; if (hh >= 224) hh -= 224;
      int w2 = wwn*7 + j + 3; if (w2 >= 224) w2 -= 224;
      if (q == 0) {
        const int rr = (wh < 31) ? 0 : ((i < 4) ? 1 : 2);
        const int cr = (wwn < 31) ? 0 : ((j < 4) ? 1 : 2);
        sid[n]  = rr*3 + cr;
        spos[n] = ((b*224 + hh)*224 + w2)*96;
      }
      const float* px = x + (size_t)(((b*224 + hh)*224 + w2)*96) + q*24;
      float v[24]; float s = 0.f, s2 = 0.f;
      const float4* p4 = (const float4*)px;
      #pragma unroll
      for (int t = 0; t < 6; ++t) { float4 u = p4[t];
        v[t*4+0]=u.x; v[t*4+1]=u.y; v[t*4+2]=u.z; v[t*4+3]=u.w; }
      #pragma unroll
      for (int c = 0; c < 24; ++c) { s += v[c]; s2 += v[c]*v[c]; }
      s  += __shfl_xor(s, 1);  s  += __shfl_xor(s, 2);
      s2 += __shfl_xor(s2, 1); s2 += __shfl_xor(s2, 2);
      const float mu = s * (1.f/96.f);
      const float rs = rsqrtf(s2*(1.f/96.f) - mu*mu + 1e-5f);
      ushort* row = xn + n*104 + q*24;
      #pragma unroll
      for (int c = 0; c < 24; ++c)
        row[c] = f2bf((v[c]-mu)*rs*g1[q*24+c] + b1v[q*24+c]);
    }
    for (int idx = tid; idx < 15*104; idx += 256) xn[49*104 + idx] = 0;  // pad rows
  }
  __syncthreads();

  // A fragments for the qkv GEMM: ALL 64 rows (12 frags, 48 VGPR), cached
  // across the whole head loop (xn is then reused as attention output ob).
  short8 a_[12];
  #pragma unroll
  for (int rt = 0; rt < 4; ++rt)
    #pragma unroll
    for (int k = 0; k < 3; ++k)
      a_[rt*3+k] = lds8(xn + (rt*16 + ln)*104 + k*32 + quad*8);

  int idrv[4], idcv[4];
  #pragma unroll
  for (int reg = 0; reg < 4; ++reg) {
    const int r = wv*16 + quad*4 + reg;
    idrv[reg] = (r < 49) ? sid[r] : -1;
  }
  #pragma unroll
  for (int nt = 0; nt < 4; ++nt) {
    const int c = nt*16 + ln;
    idcv[nt] = (c < 49) ? sid[c] : -2;
  }

  // ---- Phases 1+2: per-head qkv GEMM (B-reuse x4) + attention ----
  ushort* ob = xn;
  for (int h = 0; h < 3; ++h) {
    {
      // tileA: waves 0,1 -> Q cols, waves 2,3 -> K cols; full 64 rows each.
      const int sec  = wv >> 1;                       // 0=Q, 1=K
      const int sub  = wv & 1;
      const int colw = sec*96 + h*32 + sub*16 + ln;
      const ushort* wr = qkv_wb + colw*96 + quad*8;
      short8 b0 = lds8(wr), b1 = lds8(wr+32), b2 = lds8(wr+64);
      // tileB: V cols, split across waves: col half by wv>>1, row half by wv&1.
      const int colv = 192 + h*32 + (wv>>1)*16 + ln;
      const ushort* wr2 = qkv_wb + colv*96 + quad*8;
      short8 c0 = lds8(wr2), c1 = lds8(wr2+32), c2 = lds8(wr2+64);
      const float biasA = qkv_b[colw];
      const float biasV = qkv_b[colv];
      const int d  = sub*16 + ln;
      const int dv = (wv>>1)*16 + ln;
      #pragma unroll
      for (int rt = 0; rt < 4; ++rt) {
        floatx4 acc = {0.f,0.f,0.f,0.f};
        acc = MFMA(a_[rt*3+0], b0, acc);
        acc = MFMA(a_[rt*3+1], b1, acc);
        acc = MFMA(a_[rt*3+2], b2, acc);
        #pragma unroll
        for (int reg = 0; reg < 4; ++reg) {
          const int r = rt*16 + quad*4 + reg;
          const float val = acc[reg] + biasA;
          if (sec == 0) Qh[r*40 + d] = f2bf(val * 0.17677669529663689f);
          else          Kh[r*40 + d] = f2bf(val);
        }
      }
      const int rt0 = (wv & 1)*2;
      #pragma unroll
      for (int j = 0; j < 2; ++j) {
        floatx4 acc = {0.f,0.f,0.f,0.f};
        acc = MFMA(a_[(rt0+j)*3+0], c0, acc);
        acc = MFMA(a_[(rt0+j)*3+1], c1, acc);
        acc = MFMA(a_[(rt0+j)*3+2], c2, acc);
        #pragma unroll
        for (int reg = 0; reg < 4; ++reg) {
          const int r = (rt0+j)*16 + quad*4 + reg;
          Vh[dv*72 + r] = f2bf(acc[reg] + biasV);
        }
      }
    }
    __syncthreads();

    // QK^T + masked softmax -> Pb
    {
      short8 aq = lds8(Qh + (wv*16 + ln)*40 + quad*8);
      floatx4 sc[4];
      #pragma unroll
      for (int nt = 0; nt < 4; ++nt) {
        short8 kb = lds8(Kh + (nt*16 + ln)*40 + quad*8);
        floatx4 z = {0.f,0.f,0.f,0.f};
        sc[nt] = MFMA(aq, kb, z);               // S[r][c]
      }
      #pragma unroll
      for (int reg = 0; reg < 4; ++reg) {
        float t[4]; float mx = -1e30f;
        #pragma unroll
        for (int nt = 0; nt < 4; ++nt) {
          float tv = -1e30f;
          if (idrv[reg] >= 0 && idcv[nt] >= 0)
            tv = sc[nt][reg] + ((idrv[reg] == idcv[nt]) ? 0.f : -100.f);
          t[nt] = tv; mx = fmaxf(mx, tv);
        }
        mx = fmaxf(mx, __shfl_xor(mx, 1));
        mx = fmaxf(mx, __shfl_xor(mx, 2));
        mx = fmaxf(mx, __shfl_xor(mx, 4));
        mx = fmaxf(mx, __shfl_xor(mx, 8));
        float e[4], sum = 0.f;
        #pragma unroll
        for (int nt = 0; nt < 4; ++nt) {
          e[nt] = (t[nt] > -1e29f) ? __expf(t[nt] - mx) : 0.f;
          sum += e[nt];
        }
        sum += __shfl_xor(sum, 1);
        sum += __shfl_xor(sum, 2);
        sum += __shfl_xor(sum, 4);
        sum += __shfl_xor(sum, 8);
        const float inv = (sum > 0.f) ? 1.f/sum : 0.f;
        #pragma unroll
        for (int nt = 0; nt < 4; ++nt)
          Pb[(wv*16 + quad*4 + reg)*72 + nt*16 + ln] = f2bf(e[nt]*inv);
      }
    }
    __syncthreads();

    // P @ V -> ob columns [h*32, h*32+32)
    {
      short8 p0 = lds8(Pb + (wv*16 + ln)*72 + quad*8);
      short8 p1 = lds8(Pb + (wv*16 + ln)*72 + 32 + quad*8);
      #pragma unroll
      for (int ntd = 0; ntd < 2; ++ntd) {
        floatx4 accO = {0.f,0.f,0.f,0.f};
        accO = MFMA(p0, lds8(Vh + (ntd*16+ln)*72 + quad*8),      accO);
        accO = MFMA(p1, lds8(Vh + (ntd*16+ln)*72 + 32 + quad*8), accO);
        #pragma unroll
        for (int reg = 0; reg < 4; ++reg)
          ob[(wv*16 + quad*4 + reg)*104 + h*32 + ntd*16 + ln] = f2bf(accO[reg]);
      }
    }
    __syncthreads();
  }

  // ---- Phase 3: proj (B-reuse x4) + residual -> xrb (LDS) AND global out ----
  {
    short8 o_[12];
    #pragma unroll
    for (int rt = 0; rt < 4; ++rt)
      #pragma unroll
      for (int k = 0; k < 3; ++k)
        o_[rt*3+k] = lds8(ob + (rt*16 + ln)*104 + k*32 + quad*8);

    const int colA = wv*16 + ln;
    const ushort* wr = proj_wb + colA*96 + quad*8;
    short8 b0 = lds8(wr), b1 = lds8(wr+32), b2 = lds8(wr+64);
    const int colB = (4 + (wv>>1))*16 + ln;
    const ushort* wr2 = proj_wb + colB*96 + quad*8;
    short8 c0 = lds8(wr2), c1 = lds8(wr2+32), c2 = lds8(wr2+64);
    const float biasA = proj_b[colA], biasB = proj_b[colB];

    #pragma unroll
    for (int rt = 0; rt < 4; ++rt) {
      floatx4 acc = {0.f,0.f,0.f,0.f};
      acc = MFMA(o_[rt*3+0], b0, acc);
      acc = MFMA(o_[rt*3+1], b1, acc);
      acc = MFMA(o_[rt*3+2], b2, acc);
      #pragma unroll
      for (int reg = 0; reg < 4; ++reg) {
        const int r = rt*16 + quad*4 + reg;
        if (r < 49) {
          const int pos = spos[r] + colA;
          const float val = x[pos] + acc[reg] + biasA;
          xrb[r*96 + colA] = val;
          out[pos] = val;                        // residual persisted to global
        }
      }
    }
    const int rt0 = (wv & 1)*2;
    #pragma unroll
    for (int j = 0; j < 2; ++j) {
      floatx4 acc = {0.f,0.f,0.f,0.f};
      acc = MFMA(o_[(rt0+j)*3+0], c0, acc);
      acc = MFMA(o_[(rt0+j)*3+1], c1, acc);
      acc = MFMA(o_[(rt0+j)*3+2], c2, acc);
      #pragma unroll
      for (int reg = 0; reg < 4; ++reg) {
        const int r = (rt0+j)*16 + quad*4 + reg;
        if (r < 49) {
          const int pos = spos[r] + colB;
          const float val = x[pos] + acc[reg] + biasB;
          xrb[r*96 + colB] = val;
          out[pos] = val;
        }
      }
    }
    for (int idx = tid; idx < 15*96; idx += 256) xrb[49*96 + idx] = 0.f;  // pads
  }
  __syncthreads();

  // ---- Phase 4: LN2 from xrb -> xn (bf16) ----
  {
    const int n = tid >> 2, q = tid & 3;
    const float4* p4 = (const float4*)(xrb + n*96 + q*24);
    float v[24]; float s = 0.f, s2 = 0.f;
    #pragma unroll
    for (int t = 0; t < 6; ++t) { float4 u = p4[t];
      v[t*4+0]=u.x; v[t*4+1]=u.y; v[t*4+2]=u.z; v[t*4+3]=u.w; }
    #pragma unroll
    for (int c = 0; c < 24; ++c) { s += v[c]; s2 += v[c]*v[c]; }
    s  += __shfl_xor(s, 1);  s  += __shfl_xor(s, 2);
    s2 += __shfl_xor(s2, 1); s2 += __shfl_xor(s2, 2);
    const float mu = s * (1.f/96.f);
    const float rs = rsqrtf(s2*(1.f/96.f) - mu*mu + 1e-5f);
    ushort* row = xn + n*104 + q*24;
    #pragma unroll
    for (int c = 0; c < 24; ++c)
      row[c] = f2bf((v[c]-mu)*rs*g2[q*24+c] + b2v[q*24+c]);
  }
  __syncthreads();   // xrb dead after this point; hb overlays it

  // ---- Phase 5: MLP over hidden-column halves (hb = 64x200) ----
  // fc2 partial sums accumulate in registers across the two k-halves.
  floatx4 Cacc[3][2];
  #pragma unroll
  for (int t = 0; t < 3; ++t)
    #pragma unroll
    for (int j = 0; j < 2; ++j)
      Cacc[t][j] = (floatx4){0.f,0.f,0.f,0.f};
  const int p  = wv >> 1;          // fc2 row-pair
  const int cg = (wv & 1)*3;       // fc2 col-tile group

  for (int ch = 0; ch < 2; ++ch) {
    // fc1 half: 12 col-tiles, 3 per wave, full 64 rows (B-reuse x4)
    {
      short8 m_[12];
      #pragma unroll
      for (int rt = 0; rt < 4; ++rt)
        #pragma unroll
        for (int k = 0; k < 3; ++k)
          m_[rt*3+k] = lds8(xn + (rt*16 + ln)*104 + k*32 + quad*8);
      #pragma unroll
      for (int t = 0; t < 3; ++t) {
        const int ntl  = wv*3 + t;            // 0..11
        const int colh = ntl*16 + ln;         // 0..191
        const int gcol = ch*192 + colh;
        const ushort* wr1 = fc1_wb + gcol*96 + quad*8;
        short8 b0 = lds8(wr1), b1 = lds8(wr1+32), b2 = lds8(wr1+64);
        const float bias = fc1_b[gcol];
        #pragma unroll
        for (int rt = 0; rt < 4; ++rt) {
          floatx4 acc = {0.f,0.f,0.f,0.f};
          acc = MFMA(m_[rt*3+0], b0, acc);
          acc = MFMA(m_[rt*3+1], b1, acc);
          acc = MFMA(m_[rt*3+2], b2, acc);
          #pragma unroll
          for (int reg = 0; reg < 4; ++reg) {
            const float vv = acc[reg] + bias;
            hb[(rt*16 + quad*4 + reg)*200 + colh] =
                f2bf(0.5f*vv*(1.f + erff(vv*0.70710678118654752f)));
          }
        }
      }
    }
    __syncthreads();
    // fc2 half: wave = 2 row-tiles x 3 col-tiles, accumulate partials
    {
      short8 h_[12];
      #pragma unroll
      for (int j = 0; j < 2; ++j)
        #pragma unroll
        for (int k = 0; k < 6; ++k)
          h_[j*6+k] = lds8(hb + ((2*p+j)*16 + ln)*200 + k*32 + quad*8);
      #pragma unroll
      for (int t = 0; t < 3; ++t) {
        const int outc = (cg + t)*16 + ln;
        const ushort* wr2 = fc2_wb + outc*384 + ch*192 + quad*8;
        short8 w0 = lds8(wr2),     w1 = lds8(wr2+32),  w2 = lds8(wr2+64),
               w3 = lds8(wr2+96),  w4 = lds8(wr2+128), w5 = lds8(wr2+160);
        #pragma unroll
        for (int j = 0; j < 2; ++j) {
          floatx4 acc = Cacc[t][j];
          acc = MFMA(h_[j*6+0], w0, acc);
          acc = MFMA(h_[j*6+1], w1, acc);
          acc = MFMA(h_[j*6+2], w2, acc);
          acc = MFMA(h_[j*6+3], w3, acc);
          acc = MFMA(h_[j*6+4], w4, acc);
          acc = MFMA(h_[j*6+5], w5, acc);
          Cacc[t][j] = acc;
        }
      }
    }
    __syncthreads();
  }

  // fc2 epilogue: out[pos] += mlp (residual stored in phase 3)
  #pragma unroll
  for (int t = 0; t < 3; ++t) {
    const int outc = (cg + t)*16 + ln;
    const float bias = fc2_b[outc];
    #pragma unroll
    for (int j = 0; j < 2; ++j) {
      #pragma unroll
      for (int reg = 0; reg < 4; ++reg) {
        const int r = (2*p + j)*16 + quad*4 + reg;
        if (r < 49) {
          const int pos = spos[r] + outc;
          out[pos] += Cacc[t][j][reg] + bias;
        }
      }
    }
  }
}

extern "C" void kernel_launch(void* const* d_in, const int* in_sizes, int n_in,
                              void* d_out, int out_size, void* d_ws, size_t ws_size,
                              hipStream_t stream) {
  // Size-based remap (identity in practice — kept as insurance).
  int ix=-1, iq=-1, ip=-1, if1=-1, if2=-1, largest=0;
  for (int i = 0; i < n_in; ++i) {
    const int s = in_sizes[i];
    if (s == 38535168 && ix < 0) ix = i;
    else if (s == 27648 && iq < 0) iq = i;
    else if (s == 9216 && ip < 0) ip = i;
    else if (s == 36864) { if (if1 < 0) if1 = i; else if (if2 < 0) if2 = i; }
    if (in_sizes[i] >= in_sizes[largest]) largest = i;
  }
  if (ix < 0) ix = largest;
  if (iq < 0) iq = 4;
  if (ip < 0) ip = 6;
  if (if1 < 0) if1 = 10;
  if (if2 < 0) if2 = 12;

  const float* x    = (const float*)d_in[ix];
  const float* n1g  = (const float*)d_in[2];
  const float* n1b  = (const float*)d_in[3];
  const float* qkvw = (const float*)d_in[iq];
  const float* qkvb = (const float*)d_in[5];
  const float* pw   = (const float*)d_in[ip];
  const float* pb   = (const float*)d_in[7];
  const float* n2g  = (const float*)d_in[8];
  const float* n2b  = (const float*)d_in[9];
  const float* f1w  = (const float*)d_in[if1];
  const float* f1b  = (const float*)d_in[11];
  const float* f2w  = (const float*)d_in[if2];
  const float* f2b  = (const float*)d_in[13];
  float* outp = (float*)d_out;
  ushort* wb = (ushort*)d_ws;

  convw_kernel<<<432, 256, 0, stream>>>(qkvw, pw, f1w, f2w, wb);
  swin_block_kernel<<<8192, 256, 0, stream>>>(
      x, n1g, n1b, wb, qkvb, wb + 27648, pb,
      n2g, n2b, wb + 36864, f1b, wb + 73728, f2b, outp);
}